// Round 12
// baseline (112.854 us; speedup 1.0000x reference)
//
#include <hip/hip_runtime.h>
#include <hip/hip_bf16.h>

#define LAMBDA 0.75f
#define CMID 256
#define DOUT 4096

typedef __attribute__((ext_vector_type(8))) short bf16x8;   // MFMA A/B operand
typedef __attribute__((ext_vector_type(4))) float f32x4;    // MFMA C/D operand

static inline __device__ short f2bf(float f) {
    __hip_bfloat16 h = __float2bfloat16(f);
    short s; __builtin_memcpy(&s, &h, 2);
    return s;
}

// ---------------------------------------------------------------------------
// ROUND-12: wave-autonomous conv. r11 counters showed the real disease:
// occupancy 9.8%, all pipes <31% busy -- latency-bound block-phase structure
// (2 barriers x 8 serial block-rounds, VGPR 132 > 128 cliff). Fix: NO LDS,
// NO barriers, NO atomics; each wave independently computes one (b, h, half)
// strip: 128 px x 128 co. x is L2-resident (6.3MB) -- lanes build im2col
// fragments straight from global (clamped addresses + cndmask select, no OOB).
// 8192 waves = one residency round at 4 waves/SIMD (~75 VGPR < 128 cliff).
// k-slot map s=g*8+j IDENTICAL on A and B sides (any HW k-bijection works):
//   g<3: ci=g, ky=j/3, kx=j%3 (taps (0,0)..(2,1));
//   g=3: j<3 -> ci=j tap(2,2); j==3 -> bias (x-side 1.0); j>3 -> zero.
// D[px,co]: lane (g,lm) holds rows 4g..4g+3 (px) of col lm (co); hardshrink+
// fold over r, shfl_xor(16,32) over g -> per-(b,h) co partials (plain store).
// ---------------------------------------------------------------------------
__global__ __launch_bounds__(256) void conv_pool_wave(
    const float* __restrict__ x, const float* __restrict__ conv_w,
    const float* __restrict__ conv_b, float* __restrict__ part)
{
    const int wid = (blockIdx.x << 2) | (threadIdx.x >> 6);  // 0..8191
    const int l   = threadIdx.x & 63;
    const int lm  = l & 15;
    const int g   = l >> 4;

    const int b    = wid >> 8;            // 0..31
    const int rem  = wid & 255;
    const int h    = rem >> 1;            // 0..127
    const int half = rem & 1;             // co range [half*128, half*128+128)

    // ---- weights: 8 co-tiles in VGPRs; bias rides k-slot s27 ----
    bf16x8 wfrag[8];
    float  pool_s[8];
    #pragma unroll
    for (int c = 0; c < 8; ++c) {
        const int co = (half * 8 + c) * 16 + lm;
        const float* wp = conv_w + co * 27;
        float av[8];
        if (g < 3) {
            #pragma unroll
            for (int j = 0; j < 8; ++j) av[j] = wp[g * 9 + j];
        } else {
            av[0] = wp[8]; av[1] = wp[17]; av[2] = wp[26];
            av[3] = conv_b[co];                 // bias * im2col's 1.0
            av[4] = av[5] = av[6] = av[7] = 0.f;
        }
        #pragma unroll
        for (int j = 0; j < 8; ++j) wfrag[c][j] = f2bf(av[j]);
        pool_s[c] = 0.f;
    }

    const bool rvm = (h > 0), rvp = (h < 127);
    const int  hm  = rvm ? h - 1 : h;      // clamped (in-bounds) rows
    const int  hp  = rvp ? h + 1 : h;
    const f32x4 zf = (f32x4){0.f, 0.f, 0.f, 0.f};

    for (int tw = 0; tw < 8; ++tw) {
        const int px  = tw * 16 + lm;
        const bool cvm = (px > 0), cvp = (px < 127);
        const int  pm  = cvm ? px - 1 : px;  // clamped cols
        const int  pp  = cvp ? px + 1 : px;

        bf16x8 xf;
        if (g < 3) {
            const float* base = x + (b * 3 + g) * 16384;
            // clamped loads (always in-bounds) + select 0 for pad taps
            float v00 = (rvm && cvm) ? base[hm * 128 + pm] : 0.f;
            float v01 =  rvm         ? base[hm * 128 + px] : 0.f;
            float v02 = (rvm && cvp) ? base[hm * 128 + pp] : 0.f;
            float v10 =  cvm         ? base[h  * 128 + pm] : 0.f;
            float v11 =                base[h  * 128 + px];
            float v12 =  cvp         ? base[h  * 128 + pp] : 0.f;
            float v20 = (rvp && cvm) ? base[hp * 128 + pm] : 0.f;
            float v21 =  rvp         ? base[hp * 128 + px] : 0.f;
            xf[0] = f2bf(v00); xf[1] = f2bf(v01); xf[2] = f2bf(v02);
            xf[3] = f2bf(v10); xf[4] = f2bf(v11); xf[5] = f2bf(v12);
            xf[6] = f2bf(v20); xf[7] = f2bf(v21);
        } else {
            const bool vv = rvp && cvp;
            const int  o  = hp * 128 + pp;
            float t0 = vv ? x[(b * 3 + 0) * 16384 + o] : 0.f;
            float t1 = vv ? x[(b * 3 + 1) * 16384 + o] : 0.f;
            float t2 = vv ? x[(b * 3 + 2) * 16384 + o] : 0.f;
            xf[0] = f2bf(t0); xf[1] = f2bf(t1); xf[2] = f2bf(t2);
            xf[3] = f2bf(1.0f);                 // bias slot
            xf[4] = xf[5] = xf[6] = xf[7] = (short)0;
        }

        #pragma unroll
        for (int c = 0; c < 8; ++c) {
            f32x4 acc = __builtin_amdgcn_mfma_f32_16x16x32_bf16(
                xf, wfrag[c], zf, 0, 0, 0);
            float s = 0.f;
            #pragma unroll
            for (int r = 0; r < 4; ++r)
                s += (acc[r] > LAMBDA) ? acc[r] : 0.f;  // relu+hardshrink
            pool_s[c] += s;
        }
    }

    // ---- reduce over g (pixel row-groups); plain per-(b,h) store ----
    #pragma unroll
    for (int c = 0; c < 8; ++c) {
        float s = pool_s[c];
        s += __shfl_xor(s, 16, 64);
        s += __shfl_xor(s, 32, 64);
        if (l < 16)
            part[(b * 128 + h) * 256 + half * 128 + c * 16 + lm] = s;
    }
}

// ---------------------------------------------------------------------------
// Reduce: pooled[b][co] = (1/16384) * sum_h part[b][h][co]
// ---------------------------------------------------------------------------
__global__ __launch_bounds__(256) void reduce_kernel(
    const float* __restrict__ part, float* __restrict__ pooled)
{
    const int b = blockIdx.x;
    const int t = threadIdx.x;
    float s = 0.f;
    const float* pp = part + b * 128 * 256 + t;
    #pragma unroll 8
    for (int j = 0; j < 128; ++j) s += pp[j * 256];
    pooled[b * 256 + t] = s * (1.0f / 16384.0f);
}

// ---------------------------------------------------------------------------
// FC: out[b][d] = log_sigmoid(dot(pooled[b], fc_w[d]) + fc_b[d])
// ---------------------------------------------------------------------------
__global__ __launch_bounds__(256) void fc_kernel(
    const float* __restrict__ pooled, const float* __restrict__ fc_w,
    const float* __restrict__ fc_b, float* __restrict__ out)
{
    __shared__ float pool[CMID];
    const int b = blockIdx.y;
    const int t = threadIdx.x;
    pool[t] = pooled[b * CMID + t];
    __syncthreads();

    const int d = blockIdx.x * 256 + t;
    const float4* wrow = (const float4*)(fc_w + d * CMID);
    float acc = fc_b[d];
    #pragma unroll 8
    for (int k4 = 0; k4 < CMID / 4; k4++) {
        float4 wv = wrow[k4];
        acc += wv.x * pool[k4 * 4 + 0] + wv.y * pool[k4 * 4 + 1]
             + wv.z * pool[k4 * 4 + 2] + wv.w * pool[k4 * 4 + 3];
    }
    float ls = fminf(acc, 0.f) - log1pf(expf(-fabsf(acc)));
    out[b * (int)DOUT + d] = ls;
}

// ---------------------------------------------------------------------------
extern "C" void kernel_launch(void* const* d_in, const int* in_sizes, int n_in,
                              void* d_out, int out_size, void* d_ws, size_t ws_size,
                              hipStream_t stream) {
    const float* x      = (const float*)d_in[0];   // [32,3,128,128]
    const float* conv_w = (const float*)d_in[1];   // [256,3,3,3]
    const float* conv_b = (const float*)d_in[2];   // [256]
    const float* fc_w   = (const float*)d_in[3];   // [4096,256]
    const float* fc_b   = (const float*)d_in[4];   // [4096]
    float* out = (float*)d_out;                    // [32,4096]

    float* part   = (float*)d_ws;                  // [32][128][256] = 4 MB
    float* pooled = part + 32 * 128 * 256;         // [32][256] = 32 KB

    conv_pool_wave<<<2048, 256, 0, stream>>>(x, conv_w, conv_b, part);
    reduce_kernel<<<32, 256, 0, stream>>>(part, pooled);
    fc_kernel<<<dim3(16, 32), 256, 0, stream>>>(pooled, fc_w, fc_b, out);
}